// Round 13
// baseline (844.644 us; speedup 1.0000x reference)
//
#include <hip/hip_runtime.h>
#include <hip/hip_bf16.h>
#include <stdint.h>

#define B_SZ 64
#define L_SZ 2048
#define V_SZ 1024
#define H_SZ 256
#define HALF_SZ 128
#define NTOK (B_SZ * L_SZ)   // 131072
#define CH 16384             // token chunk (8 chunks)

typedef unsigned short ushort_t;
typedef __attribute__((ext_vector_type(8))) short bf16x8;
typedef __attribute__((ext_vector_type(4))) float f32x4;

__device__ __forceinline__ ushort_t f2bf(float f) {
    __hip_bfloat16 h = __float2bfloat16(f);
    return *reinterpret_cast<ushort_t*>(&h);
}

// ---------------------------------------------------------------------------
// f32 -> bf16 convert (same layout). n multiple of 1024.
// ---------------------------------------------------------------------------
__global__ __launch_bounds__(256) void cvt_bf16_k(
    const float* __restrict__ src, ushort_t* __restrict__ dst, int n)
{
    int i = (blockIdx.x * 256 + threadIdx.x) * 4;
    if (i >= n) return;
    float4 v = *(const float4*)(src + i);
    uint2 pk;
    pk.x = (uint32_t)f2bf(v.x) | ((uint32_t)f2bf(v.y) << 16);
    pk.y = (uint32_t)f2bf(v.z) | ((uint32_t)f2bf(v.w) << 16);
    *(uint2*)(dst + i) = pk;
}

// ---------------------------------------------------------------------------
// dst[n*K + k] = bf16(src[k*N + n])  — weight transpose + convert (tiny).
// ---------------------------------------------------------------------------
__global__ __launch_bounds__(256) void transpose_cvt_k(
    const float* __restrict__ src, ushort_t* __restrict__ dst, int K, int N)
{
    int idx = blockIdx.x * 256 + threadIdx.x;
    if (idx >= K * N) return;
    int n = idx / K;
    int k = idx - n * K;
    dst[idx] = f2bf(src[(size_t)k * N + n]);
}

// ---------------------------------------------------------------------------
// bf16 MFMA GEMM: C[128 x 128-tile] = A[M][K] @ BT[N][K]^T, 256 thr / 4 waves.
// BK=64, LDS XOR-swizzled (chunk ^= row&7) for conflict-free ds_read_b128.
// MODE 1: A row = embed_bf[seq[m]]; C = relu(acc+bias) -> bf16
// MODE 2: A = t1 bf16;  C = acc + bias + embed_f32[seq[m]][n] -> f32
// MODE 3: A = h bf16;   C = acc + bias -> f32
// ---------------------------------------------------------------------------
template <int MODE, int K, int N>
__global__ __launch_bounds__(256) void gemm_mfma(
    const ushort_t* __restrict__ A, const ushort_t* __restrict__ BT,
    const float* __restrict__ bias, void* __restrict__ Cp,
    const int* __restrict__ seq, const float* __restrict__ embed)
{
    __shared__ __align__(16) ushort_t Asm[128 * 64];
    __shared__ __align__(16) ushort_t Bsm[128 * 64];

    const int tid = threadIdx.x;
    const int m0 = blockIdx.x * 128;
    const int n0 = blockIdx.y * 128;
    const int w = tid >> 6;
    const int l = tid & 63;
    const int wr = w >> 1;   // wave tile row (0..1)
    const int wc = w & 1;    // wave tile col (0..1)

    // staging row base pointers (rows fixed across K-loop)
    const ushort_t* arow[4];
    const ushort_t* brow[4];
#pragma unroll
    for (int i = 0; i < 4; ++i) {
        const int flat = i * 256 + tid;       // 0..1023
        const int r = flat >> 3;              // 0..127
        const int gr = (MODE == 1) ? seq[m0 + r] : (m0 + r);
        arow[i] = A + (size_t)gr * K;
        brow[i] = BT + (size_t)(n0 + r) * K;
    }

    f32x4 acc[4][4];
#pragma unroll
    for (int mi = 0; mi < 4; ++mi)
#pragma unroll
        for (int nj = 0; nj < 4; ++nj)
            acc[mi][nj] = (f32x4){0.f, 0.f, 0.f, 0.f};

    for (int kt = 0; kt < K / 64; ++kt) {
#pragma unroll
        for (int i = 0; i < 4; ++i) {
            const int flat = i * 256 + tid;
            const int r = flat >> 3;          // tile row
            const int c = flat & 7;           // 16B chunk within 128B row
            const int cs = c ^ (r & 7);       // swizzled chunk
            uint4 av = *(const uint4*)(arow[i] + kt * 64 + c * 8);
            *(uint4*)&Asm[r * 64 + cs * 8] = av;
            uint4 bv = *(const uint4*)(brow[i] + kt * 64 + c * 8);
            *(uint4*)&Bsm[r * 64 + cs * 8] = bv;
        }
        __syncthreads();
#pragma unroll
        for (int kh = 0; kh < 2; ++kh) {
            bf16x8 af[4], bfr[4];
#pragma unroll
            for (int mi = 0; mi < 4; ++mi) {
                const int r = wr * 64 + mi * 16 + (l & 15);
                const int c = (kh * 4 + (l >> 4)) ^ (r & 7);
                af[mi] = *(const bf16x8*)&Asm[r * 64 + c * 8];
            }
#pragma unroll
            for (int nj = 0; nj < 4; ++nj) {
                const int r = wc * 64 + nj * 16 + (l & 15);
                const int c = (kh * 4 + (l >> 4)) ^ (r & 7);
                bfr[nj] = *(const bf16x8*)&Bsm[r * 64 + c * 8];
            }
#pragma unroll
            for (int mi = 0; mi < 4; ++mi)
#pragma unroll
                for (int nj = 0; nj < 4; ++nj)
                    acc[mi][nj] = __builtin_amdgcn_mfma_f32_16x16x32_bf16(
                        af[mi], bfr[nj], acc[mi][nj], 0, 0, 0);
        }
        __syncthreads();
    }

    // epilogue: C/D layout col = lane&15, row = (lane>>4)*4 + reg
    const int cl = l & 15;
    const int rg = l >> 4;
    float bv[4];
#pragma unroll
    for (int nj = 0; nj < 4; ++nj)
        bv[nj] = bias[n0 + wc * 64 + nj * 16 + cl];

#pragma unroll
    for (int mi = 0; mi < 4; ++mi) {
#pragma unroll
        for (int i = 0; i < 4; ++i) {
            const int row = m0 + wr * 64 + mi * 16 + rg * 4 + i;  // chunk-local
            const float* erow = (MODE == 2)
                ? (embed + (size_t)seq[row] * H_SZ) : nullptr;
#pragma unroll
            for (int nj = 0; nj < 4; ++nj) {
                const int gn = n0 + wc * 64 + nj * 16 + cl;
                float v = acc[mi][nj][i] + bv[nj];
                if (MODE == 1) {
                    v = fmaxf(v, 0.f);
                    ((ushort_t*)Cp)[(size_t)row * N + gn] = f2bf(v);
                } else if (MODE == 2) {
                    ((float*)Cp)[(size_t)row * N + gn] = v + erow[gn];
                } else {
                    ((float*)Cp)[(size_t)row * N + gn] = v;
                }
            }
        }
    }
}

// ---------------------------------------------------------------------------
// LayerNorm over H=256: one wave per token, 4 tokens per block (chunk-local).
// ---------------------------------------------------------------------------
__global__ __launch_bounds__(256) void ln_k(
    const float* __restrict__ x, const float* __restrict__ g,
    const float* __restrict__ bt, ushort_t* __restrict__ h)
{
    const int token = blockIdx.x * 4 + (threadIdx.x >> 6);
    const int lane = threadIdx.x & 63;
    const float* xr = x + (size_t)token * H_SZ + lane * 4;
    const float4 v = *(const float4*)xr;
    float s = v.x + v.y + v.z + v.w;
    float sq = v.x * v.x + v.y * v.y + v.z * v.z + v.w * v.w;
#pragma unroll
    for (int m = 1; m < 64; m <<= 1) {
        s += __shfl_xor(s, m);
        sq += __shfl_xor(sq, m);
    }
    const float mu = s * (1.f / H_SZ);
    const float var = sq * (1.f / H_SZ) - mu * mu;
    const float rs = rsqrtf(var + 1e-5f);
    const int idx = lane * 4;
    const float4 gg = *(const float4*)(g + idx);
    const float4 bb = *(const float4*)(bt + idx);
    ushort_t o0 = f2bf((v.x - mu) * rs * gg.x + bb.x);
    ushort_t o1 = f2bf((v.y - mu) * rs * gg.y + bb.y);
    ushort_t o2 = f2bf((v.z - mu) * rs * gg.z + bb.z);
    ushort_t o3 = f2bf((v.w - mu) * rs * gg.w + bb.w);
    uint2 pk;
    pk.x = (uint32_t)o0 | ((uint32_t)o1 << 16);
    pk.y = (uint32_t)o2 | ((uint32_t)o3 << 16);
    *(uint2*)(h + (size_t)token * H_SZ + idx) = pk;
}

// ---------------------------------------------------------------------------
// gram8_k: per (pair, 8-token block) precompute solve data. Record (48 f32):
//   [0..27]  W[i][j] (i>j, idx=i(i-1)/2+j): strictly-lower part of
//            (I+L)^{-1}, where L[i][j] = alpha_j * (k_i . k_j).
//            => in the scan, d = a + W a (all terms independent).
//   [28..35] alpha_i = beta_i / (|k_i|^2 + 1e-6)
//   [36..43] beta_i  (0 for token L-1; 1 for s-half; (t+1)/L for e-half)
// Token i=0 in a block is the HIGHEST token (t = 8*bi+7). 32768 waves.
// ---------------------------------------------------------------------------
__global__ __launch_bounds__(256) void gram8_k(
    const float* __restrict__ proj, float* __restrict__ g8)
{
    const int pair = blockIdx.y;               // 0..127
    const int b = pair >> 1;
    const int half = pair & 1;
    const int bi = blockIdx.x * 4 + (threadIdx.x >> 6);   // 0..255
    const int l = threadIdx.x & 63;

    const float* kbase = proj + (size_t)b * L_SZ * H_SZ + half * HALF_SZ;

    float kx[8], ky[8];
#pragma unroll
    for (int i = 0; i < 8; ++i) {
        const int tok = bi * 8 + 7 - i;
        const float2 t = *(const float2*)(kbase + (size_t)tok * H_SZ + 2 * l);
        kx[i] = t.x; ky[i] = t.y;
    }

    float r[36];
#pragma unroll
    for (int i = 0; i < 8; ++i)
        r[i] = kx[i] * kx[i] + ky[i] * ky[i];
#pragma unroll
    for (int i = 1; i < 8; ++i)
#pragma unroll
        for (int j = 0; j < i; ++j)
            r[8 + i * (i - 1) / 2 + j] = kx[i] * kx[j] + ky[i] * ky[j];

#pragma unroll
    for (int m = 1; m < 64; m <<= 1)
#pragma unroll
        for (int t = 0; t < 36; ++t)
            r[t] += __shfl_xor(r[t], m);

    const float invL = 1.0f / (float)L_SZ;
    float al[8], be[8];
#pragma unroll
    for (int i = 0; i < 8; ++i) {
        const int tok = bi * 8 + 7 - i;
        const float bet = (tok == L_SZ - 1)
            ? 0.f : (half ? (float)(tok + 1) * invL : 1.0f);
        be[i] = bet;
        al[i] = bet / (r[i] + 1e-6f);
    }

    // L (strictly lower), then W = (I+L)^{-1} - I by column-wise forward subst.
    float Lw[28];
#pragma unroll
    for (int i = 1; i < 8; ++i)
#pragma unroll
        for (int j = 0; j < i; ++j)
            Lw[i * (i - 1) / 2 + j] = al[j] * r[8 + i * (i - 1) / 2 + j];
    float Wv[28];
#pragma unroll
    for (int j = 0; j < 7; ++j)
#pragma unroll
        for (int i = j + 1; i < 8; ++i) {
            float s = Lw[i * (i - 1) / 2 + j];
#pragma unroll
            for (int m = j + 1; m < i; ++m)
                s += Lw[i * (i - 1) / 2 + m] * Wv[m * (m - 1) / 2 + j];
            Wv[i * (i - 1) / 2 + j] = -s;
        }

    if (l == 0) {
        float* out = g8 + ((size_t)pair * 256 + bi) * 48;
#pragma unroll
        for (int t = 0; t < 28; ++t) out[t] = Wv[t];
#pragma unroll
        for (int i = 0; i < 8; ++i) {
            out[28 + i] = al[i];
            out[36 + i] = be[i];
        }
    }
}

// ---------------------------------------------------------------------------
// scan_bw8_k: backward vector scan, W=8 windows, precomputed inverted Grams.
// One wave per (b,half). 3-buffer pipeline, prefetch depth 2.
// ROUND-13 CHANGE (only this kernel): DELAYED KEEP — each iteration KEEPs the
// buffer loaded in the PREVIOUS iteration (consumed NEXT iteration), so the
// forced s_waitcnt sits ~2 bodies after load issue (> HBM latency) instead of
// inside the issuing iteration (round-12: ~600cy exposed per iter). A
// "memory"-clobber pin after the load issue keeps the scheduler from sinking
// the loads down to the KEEP point.
// ---------------------------------------------------------------------------
__global__ __launch_bounds__(64, 1) void scan_bw8_k(
    const float* __restrict__ proj, const float* __restrict__ g8,
    float* __restrict__ cbuf)
{
    const int pair = blockIdx.x;        // 0..127
    const int b = pair >> 1;
    const int half = pair & 1;
    const int l = threadIdx.x;          // 0..63, owns elems 2l, 2l+1

    const float* kbase = proj + (size_t)b * L_SZ * H_SZ + half * HALF_SZ;
    const float* gbase = g8 + (size_t)pair * 256 * 48;

    float vx, vy, cx = 0.f, cy = 0.f;
    {
        const float2 q = *(const float2*)(kbase + (size_t)(L_SZ - 1) * H_SZ + 2 * l);
        vx = q.x; vy = q.y;
    }

    float kAx[8], kAy[8], kBx[8], kBy[8], kCx[8], kCy[8];
    float gA[48], gB[48], gC[48];

#define LOADK(KX, KY, blk) {                                                  \
    const int bb_ = (blk) < 0 ? 0 : (blk);                                    \
    const float* kb_ = kbase + (size_t)bb_ * 8 * H_SZ + 2 * l;                \
    _Pragma("unroll")                                                         \
    for (int i_ = 0; i_ < 8; ++i_) {                                          \
        const float2 t_ = *(const float2*)(kb_ + (size_t)(7 - i_) * H_SZ);    \
        KX[i_] = t_.x; KY[i_] = t_.y;                                         \
    } }

#define LOADG(GG, blk) {                                                      \
    const int bb_ = (blk) < 0 ? 0 : (blk);                                    \
    const float* gs_ = gbase + (size_t)bb_ * 48;                              \
    _Pragma("unroll")                                                         \
    for (int i_ = 0; i_ < 12; ++i_) {                                         \
        const float4 t_ = *(const float4*)(gs_ + 4 * i_);                     \
        GG[4*i_+0] = t_.x; GG[4*i_+1] = t_.y;                                 \
        GG[4*i_+2] = t_.z; GG[4*i_+3] = t_.w;                                 \
    } }

#define KEEP8(A0,A1,A2,A3,A4,A5,A6,A7)                                        \
    asm volatile("" :: "v"(A0), "v"(A1), "v"(A2), "v"(A3),                    \
                       "v"(A4), "v"(A5), "v"(A6), "v"(A7));

#define KEEPK(KX, KY)                                                         \
    KEEP8(KX[0],KX[1],KX[2],KX[3],KX[4],KX[5],KX[6],KX[7])                    \
    KEEP8(KY[0],KY[1],KY[2],KY[3],KY[4],KY[5],KY[6],KY[7])

#define KEEPG(GG)                                                             \
    KEEP8(GG[0],GG[1],GG[2],GG[3],GG[4],GG[5],GG[6],GG[7])                    \
    KEEP8(GG[8],GG[9],GG[10],GG[11],GG[12],GG[13],GG[14],GG[15])              \
    KEEP8(GG[16],GG[17],GG[18],GG[19],GG[20],GG[21],GG[22],GG[23])            \
    KEEP8(GG[24],GG[25],GG[26],GG[27],GG[28],GG[29],GG[30],GG[31])            \
    KEEP8(GG[32],GG[33],GG[34],GG[35],GG[36],GG[37],GG[38],GG[39])            \
    KEEP8(GG[40],GG[41],GG[42],GG[43],GG[44],GG[45],GG[46],GG[47])

// One 8-step window.
//   CUR  = buffer consumed this iteration
//   PF   = buffer receiving the prefetch of block (bi_-2)
//   NXT  = buffer consumed NEXT iteration (loaded last iteration) — KEEP this
#define ITER(bi_, KCX, KCY, GC, KFX, KFY, GF, KNX, KNY, GN, DOPF, DOKEEP) {   \
    if (DOPF) {                                                               \
        LOADK(KFX, KFY, (bi_) - 2) LOADG(GF, (bi_) - 2)                       \
        asm volatile("" ::: "memory");  /* pin load issue point */            \
    }                                                                         \
    float a_[8];                                                              \
    _Pragma("unroll")                                                         \
    for (int i_ = 0; i_ < 8; ++i_)                                            \
        a_[i_] = KCX[i_] * vx + KCY[i_] * vy;                                 \
    _Pragma("unroll")                                                         \
    for (int m_ = 1; m_ < 64; m_ <<= 1)                                       \
        _Pragma("unroll")                                                     \
        for (int i_ = 0; i_ < 8; ++i_)                                        \
            a_[i_] += __shfl_xor(a_[i_], m_);                                 \
    /* d = a + W a : independent terms, shallow trees */                      \
    float d_[8];                                                              \
    d_[0] = a_[0];                                                            \
    d_[1] = fmaf(GC[0], a_[0], a_[1]);                                        \
    d_[2] = fmaf(GC[1], a_[0], a_[2]) + GC[2] * a_[1];                        \
    d_[3] = (fmaf(GC[3], a_[0], a_[3]) + GC[4] * a_[1]) + GC[5] * a_[2];      \
    d_[4] = (fmaf(GC[6], a_[0], a_[4]) + GC[7] * a_[1])                       \
          + (GC[8] * a_[2] + GC[9] * a_[3]);                                  \
    d_[5] = ((fmaf(GC[10], a_[0], a_[5]) + GC[11] * a_[1])                    \
          + (GC[12] * a_[2] + GC[13] * a_[3])) + GC[14] * a_[4];              \
    d_[6] = ((fmaf(GC[15], a_[0], a_[6]) + GC[16] * a_[1])                    \
          + (GC[17] * a_[2] + GC[18] * a_[3]))                                \
          + (GC[19] * a_[4] + GC[20] * a_[5]);                                \
    d_[7] = ((fmaf(GC[21], a_[0], a_[7]) + GC[22] * a_[1])                    \
          + (GC[23] * a_[2] + GC[24] * a_[3]))                                \
          + ((GC[25] * a_[4] + GC[26] * a_[5]) + GC[27] * a_[6]);             \
    float ad_[8], bd_[8];                                                     \
    _Pragma("unroll")                                                         \
    for (int i_ = 0; i_ < 8; ++i_) {                                          \
        ad_[i_] = GC[28 + i_] * d_[i_];                                       \
        bd_[i_] = GC[36 + i_] * d_[i_];                                       \
    }                                                                         \
    const float sx_ = (fmaf(ad_[0], KCX[0], ad_[1] * KCX[1])                  \
                     + fmaf(ad_[2], KCX[2], ad_[3] * KCX[3]))                 \
                    + (fmaf(ad_[4], KCX[4], ad_[5] * KCX[5])                  \
                     + fmaf(ad_[6], KCX[6], ad_[7] * KCX[7]));                \
    const float sy_ = (fmaf(ad_[0], KCY[0], ad_[1] * KCY[1])                  \
                     + fmaf(ad_[2], KCY[2], ad_[3] * KCY[3]))                 \
                    + (fmaf(ad_[4], KCY[4], ad_[5] * KCY[5])                  \
                     + fmaf(ad_[6], KCY[6], ad_[7] * KCY[7]));                \
    const float tx_ = (fmaf(bd_[0], KCX[0], bd_[1] * KCX[1])                  \
                     + fmaf(bd_[2], KCX[2], bd_[3] * KCX[3]))                 \
                    + (fmaf(bd_[4], KCX[4], bd_[5] * KCX[5])                  \
                     + fmaf(bd_[6], KCX[6], bd_[7] * KCX[7]));                \
    const float ty_ = (fmaf(bd_[0], KCY[0], bd_[1] * KCY[1])                  \
                     + fmaf(bd_[2], KCY[2], bd_[3] * KCY[3]))                 \
                    + (fmaf(bd_[4], KCY[4], bd_[5] * KCY[5])                  \
                     + fmaf(bd_[6], KCY[6], bd_[7] * KCY[7]));                \
    vx -= sx_; vy -= sy_; cx += tx_; cy += ty_;                               \
    if (DOKEEP) { KEEPK(KNX, KNY) KEEPG(GN) }  /* delayed keep: next-used */  \
    }

    // init: block 255 -> A, block 254 -> B
    LOADK(kAx, kAy, 255) LOADG(gA, 255)
    LOADK(kBx, kBy, 254) LOADG(gB, 254)

    int bi = 255;
#pragma unroll 1
    for (int t3 = 0; t3 < 85; ++t3) {
        // consume A, pf->C (bi-2), keep B (loaded prev iter, used next)
        ITER(bi,     kAx, kAy, gA, kCx, kCy, gC, kBx, kBy, gB, 1, 1)
        // consume B, pf->A (bi-3), keep C
        ITER(bi - 1, kBx, kBy, gB, kAx, kAy, gA, kCx, kCy, gC, 1, 1)
        // consume C, pf->B (bi-4), keep A
        ITER(bi - 2, kCx, kCy, gC, kBx, kBy, gB, kAx, kAy, gA, 1, 1)
        bi -= 3;
    }
    // after loop: bi == 0, block 0 resides in A (loaded when bi was 2)
    ITER(0, kAx, kAy, gA, kBx, kBy, gB, kCx, kCy, gC, 0, 0)

#undef ITER
#undef KEEPG
#undef KEEPK
#undef KEEP8
#undef LOADG
#undef LOADK

    cbuf[b * H_SZ + half * HALF_SZ + 2 * l] = cx;
    cbuf[b * H_SZ + half * HALF_SZ + 2 * l + 1] = cy;
}

// ---------------------------------------------------------------------------
// out[b, v] = sum_h c[b,h] * out_w[h,v] + out_b[v]   (f32 store)
// ---------------------------------------------------------------------------
__global__ __launch_bounds__(256) void out_k(
    const float* __restrict__ c, const float* __restrict__ w,
    const float* __restrict__ ob, float* __restrict__ out)
{
    const int b = blockIdx.x >> 2;
    const int v = ((blockIdx.x & 3) << 8) + threadIdx.x;
    const float* cb = c + b * H_SZ;
    float acc = ob[v];
#pragma unroll 4
    for (int hh = 0; hh < H_SZ; ++hh)
        acc = fmaf(cb[hh], w[(size_t)hh * V_SZ + v], acc);
    out[(size_t)b * V_SZ + v] = acc;
}

// ---------------------------------------------------------------------------
extern "C" void kernel_launch(void* const* d_in, const int* in_sizes, int n_in,
                              void* d_out, int out_size, void* d_ws, size_t ws_size,
                              hipStream_t stream)
{
    const int*   seq   = (const int*)d_in[0];
    const float* embed = (const float*)d_in[1];
    const float* w1    = (const float*)d_in[2];
    const float* b1    = (const float*)d_in[3];
    const float* w2    = (const float*)d_in[4];
    const float* b2    = (const float*)d_in[5];
    const float* ln_g  = (const float*)d_in[6];
    const float* ln_b  = (const float*)d_in[7];
    const float* kp_w  = (const float*)d_in[8];
    const float* kp_b  = (const float*)d_in[9];
    const float* out_w = (const float*)d_in[10];
    const float* out_b = (const float*)d_in[11];

    char* ws = (char*)d_ws;
    size_t off = 0;
    auto alloc = [&](size_t bytes) -> void* {
        void* p = ws + off;
        off += (bytes + 255) & ~(size_t)255;
        return p;
    };

    float*    proj = (float*)alloc((size_t)NTOK * H_SZ * sizeof(float));     // 128 MB
    ushort_t* t1_c = (ushort_t*)alloc((size_t)CH * 512 * sizeof(ushort_t));  // 16 MB
    float*    x_c  = (float*)alloc((size_t)CH * H_SZ * sizeof(float));       // 16 MB
    ushort_t* h_c  = (ushort_t*)alloc((size_t)CH * H_SZ * sizeof(ushort_t)); // 8 MB
    float*    g8   = (float*)alloc((size_t)128 * 256 * 48 * sizeof(float) + 256); // 6.3 MB
    float*    cbuf = (float*)alloc((size_t)B_SZ * H_SZ * sizeof(float));
    // bf16 weight copies
    ushort_t* embed_bf = (ushort_t*)alloc((size_t)V_SZ * H_SZ * 2);          // 512 KB
    ushort_t* w1T = (ushort_t*)alloc((size_t)512 * 256 * 2);                 // 256 KB
    ushort_t* w2T = (ushort_t*)alloc((size_t)256 * 512 * 2);                 // 256 KB
    ushort_t* kpT = (ushort_t*)alloc((size_t)256 * 256 * 2);                 // 128 KB
    float*    outp = (float*)d_out;

    const dim3 blk(256);

    // weight preconversion (bf16 / transposed-bf16)
    cvt_bf16_k<<<dim3((V_SZ * H_SZ) / 1024), blk, 0, stream>>>(
        embed, embed_bf, V_SZ * H_SZ);
    transpose_cvt_k<<<dim3((256 * 512) / 256), blk, 0, stream>>>(w1, w1T, 256, 512);
    transpose_cvt_k<<<dim3((512 * 256) / 256), blk, 0, stream>>>(w2, w2T, 512, 256);
    transpose_cvt_k<<<dim3((256 * 256) / 256), blk, 0, stream>>>(kp_w, kpT, 256, 256);

    for (int c = 0; c < NTOK / CH; ++c) {
        const int base = c * CH;
        const int* seq_c = seq + base;
        // GEMM1: t1 = relu(embed[seq] @ w1 + b1)     M=CH K=256 N=512
        gemm_mfma<1, 256, 512><<<dim3(CH / 128, 4), blk, 0, stream>>>(
            embed_bf, w1T, b1, t1_c, seq_c, nullptr);
        // GEMM2: x = t1 @ w2 + b2 + embed[seq]       M=CH K=512 N=256
        gemm_mfma<2, 512, 256><<<dim3(CH / 128, 2), blk, 0, stream>>>(
            t1_c, w2T, b2, x_c, seq_c, embed);
        // LN: h = LN(x) * g + b  (bf16)
        ln_k<<<dim3(CH / 4), blk, 0, stream>>>(x_c, ln_g, ln_b, h_c);
        // GEMM3: proj = h @ kp_w + kp_b              M=CH K=256 N=256
        gemm_mfma<3, 256, 256><<<dim3(CH / 128, 2), blk, 0, stream>>>(
            h_c, kpT, kp_b, proj + (size_t)base * H_SZ, seq_c, nullptr);
    }

    // parallel precompute of inverted 8x8 block Grams + coefficients
    gram8_k<<<dim3(64, 128), blk, 0, stream>>>(proj, g8);
    // serial backward vector scan with precomputed inverted Grams
    scan_bw8_k<<<dim3(128), dim3(64), 0, stream>>>(proj, g8, cbuf);
    out_k<<<dim3(B_SZ * 4), blk, 0, stream>>>(cbuf, out_w, out_b, outp);
}

// Round 14
// 760.332 us; speedup vs baseline: 1.1109x; 1.1109x over previous
//
#include <hip/hip_runtime.h>
#include <hip/hip_bf16.h>
#include <stdint.h>

#define B_SZ 64
#define L_SZ 2048
#define V_SZ 1024
#define H_SZ 256
#define HALF_SZ 128
#define NTOK (B_SZ * L_SZ)   // 131072
#define CH 16384             // token chunk (8 chunks)

typedef unsigned short ushort_t;
typedef unsigned int u32;
typedef __attribute__((ext_vector_type(8))) short bf16x8;
typedef __attribute__((ext_vector_type(4))) float f32x4;

#define AS1 __attribute__((address_space(1)))
#define AS3 __attribute__((address_space(3)))

__device__ __forceinline__ ushort_t f2bf(float f) {
    __hip_bfloat16 h = __float2bfloat16(f);
    return *reinterpret_cast<ushort_t*>(&h);
}

// ---------------------------------------------------------------------------
// f32 -> bf16 convert (same layout). n multiple of 1024.
// ---------------------------------------------------------------------------
__global__ __launch_bounds__(256) void cvt_bf16_k(
    const float* __restrict__ src, ushort_t* __restrict__ dst, int n)
{
    int i = (blockIdx.x * 256 + threadIdx.x) * 4;
    if (i >= n) return;
    float4 v = *(const float4*)(src + i);
    uint2 pk;
    pk.x = (uint32_t)f2bf(v.x) | ((uint32_t)f2bf(v.y) << 16);
    pk.y = (uint32_t)f2bf(v.z) | ((uint32_t)f2bf(v.w) << 16);
    *(uint2*)(dst + i) = pk;
}

// ---------------------------------------------------------------------------
// dst[n*K + k] = bf16(src[k*N + n])  — weight transpose + convert (tiny).
// ---------------------------------------------------------------------------
__global__ __launch_bounds__(256) void transpose_cvt_k(
    const float* __restrict__ src, ushort_t* __restrict__ dst, int K, int N)
{
    int idx = blockIdx.x * 256 + threadIdx.x;
    if (idx >= K * N) return;
    int n = idx / K;
    int k = idx - n * K;
    dst[idx] = f2bf(src[(size_t)k * N + n]);
}

// ---------------------------------------------------------------------------
// bf16 MFMA GEMM: C[128 x 128-tile] = A[M][K] @ BT[N][K]^T, 256 thr / 4 waves.
// BK=64. ROUND-14: staging via global_load_lds (m97 pattern): linear LDS dest
// (wave-uniform base + lane*16) + PRE-SWIZZLED per-lane global source.
// For slot row r = w*32+i*8+(l>>3): r&7 == l>>3, so the source chunk is
// c = (l&7)^(l>>3) — lane-constant. Read-side swizzle unchanged (rule #21:
// source permutation == read permutation).
// MODE 1: A row = embed_bf[seq[m]]; C = relu(acc+bias) -> bf16
// MODE 2: A = t1 bf16;  C = acc + bias + embed_f32[seq[m]][n] -> f32
// MODE 3: A = h bf16;   C = acc + bias -> f32
// ---------------------------------------------------------------------------
template <int MODE, int K, int N>
__global__ __launch_bounds__(256) void gemm_mfma(
    const ushort_t* __restrict__ A, const ushort_t* __restrict__ BT,
    const float* __restrict__ bias, void* __restrict__ Cp,
    const int* __restrict__ seq, const float* __restrict__ embed)
{
    __shared__ __align__(16) ushort_t Asm[128 * 64];
    __shared__ __align__(16) ushort_t Bsm[128 * 64];

    const int tid = threadIdx.x;
    const int m0 = blockIdx.x * 128;
    const int n0 = blockIdx.y * 128;
    const int w = tid >> 6;
    const int l = tid & 63;
    const int wr = w >> 1;   // wave tile row (0..1)
    const int wc = w & 1;    // wave tile col (0..1)

    // pre-swizzled global source offset (ushort units): chunk (l&7)^(l>>3)
    const int swz = (((l & 7) ^ (l >> 3)) * 8);
    const ushort_t* aptr[4];
    const ushort_t* bptr[4];
#pragma unroll
    for (int i = 0; i < 4; ++i) {
        const int r = w * 32 + i * 8 + (l >> 3);   // LDS row this lane fills
        const int gr = (MODE == 1) ? seq[m0 + r] : (m0 + r);
        aptr[i] = A + (size_t)gr * K + swz;
        bptr[i] = BT + (size_t)(n0 + r) * K + swz;
    }

    f32x4 acc[4][4];
#pragma unroll
    for (int mi = 0; mi < 4; ++mi)
#pragma unroll
        for (int nj = 0; nj < 4; ++nj)
            acc[mi][nj] = (f32x4){0.f, 0.f, 0.f, 0.f};

    for (int kt = 0; kt < K / 64; ++kt) {
#pragma unroll
        for (int i = 0; i < 4; ++i) {
            // wave-uniform LDS base: rows w*32+i*8 .. +7 (8 rows x 128B = 1KB)
            __builtin_amdgcn_global_load_lds(
                (const AS1 u32*)(aptr[i] + kt * 64),
                (AS3 u32*)&Asm[(w * 32 + i * 8) * 64], 16, 0, 0);
            __builtin_amdgcn_global_load_lds(
                (const AS1 u32*)(bptr[i] + kt * 64),
                (AS3 u32*)&Bsm[(w * 32 + i * 8) * 64], 16, 0, 0);
        }
        __syncthreads();
#pragma unroll
        for (int kh = 0; kh < 2; ++kh) {
            bf16x8 af[4], bfr[4];
#pragma unroll
            for (int mi = 0; mi < 4; ++mi) {
                const int r = wr * 64 + mi * 16 + (l & 15);
                const int c = (kh * 4 + (l >> 4)) ^ (r & 7);
                af[mi] = *(const bf16x8*)&Asm[r * 64 + c * 8];
            }
#pragma unroll
            for (int nj = 0; nj < 4; ++nj) {
                const int r = wc * 64 + nj * 16 + (l & 15);
                const int c = (kh * 4 + (l >> 4)) ^ (r & 7);
                bfr[nj] = *(const bf16x8*)&Bsm[r * 64 + c * 8];
            }
#pragma unroll
            for (int mi = 0; mi < 4; ++mi)
#pragma unroll
                for (int nj = 0; nj < 4; ++nj)
                    acc[mi][nj] = __builtin_amdgcn_mfma_f32_16x16x32_bf16(
                        af[mi], bfr[nj], acc[mi][nj], 0, 0, 0);
        }
        __syncthreads();
    }

    // epilogue: C/D layout col = lane&15, row = (lane>>4)*4 + reg
    const int cl = l & 15;
    const int rg = l >> 4;
    float bv[4];
#pragma unroll
    for (int nj = 0; nj < 4; ++nj)
        bv[nj] = bias[n0 + wc * 64 + nj * 16 + cl];

#pragma unroll
    for (int mi = 0; mi < 4; ++mi) {
#pragma unroll
        for (int i = 0; i < 4; ++i) {
            const int row = m0 + wr * 64 + mi * 16 + rg * 4 + i;  // chunk-local
            const float* erow = (MODE == 2)
                ? (embed + (size_t)seq[row] * H_SZ) : nullptr;
#pragma unroll
            for (int nj = 0; nj < 4; ++nj) {
                const int gn = n0 + wc * 64 + nj * 16 + cl;
                float v = acc[mi][nj][i] + bv[nj];
                if (MODE == 1) {
                    v = fmaxf(v, 0.f);
                    ((ushort_t*)Cp)[(size_t)row * N + gn] = f2bf(v);
                } else if (MODE == 2) {
                    ((float*)Cp)[(size_t)row * N + gn] = v + erow[gn];
                } else {
                    ((float*)Cp)[(size_t)row * N + gn] = v;
                }
            }
        }
    }
}

// ---------------------------------------------------------------------------
// LayerNorm over H=256: one wave per token, 4 tokens per block (chunk-local).
// ---------------------------------------------------------------------------
__global__ __launch_bounds__(256) void ln_k(
    const float* __restrict__ x, const float* __restrict__ g,
    const float* __restrict__ bt, ushort_t* __restrict__ h)
{
    const int token = blockIdx.x * 4 + (threadIdx.x >> 6);
    const int lane = threadIdx.x & 63;
    const float* xr = x + (size_t)token * H_SZ + lane * 4;
    const float4 v = *(const float4*)xr;
    float s = v.x + v.y + v.z + v.w;
    float sq = v.x * v.x + v.y * v.y + v.z * v.z + v.w * v.w;
#pragma unroll
    for (int m = 1; m < 64; m <<= 1) {
        s += __shfl_xor(s, m);
        sq += __shfl_xor(sq, m);
    }
    const float mu = s * (1.f / H_SZ);
    const float var = sq * (1.f / H_SZ) - mu * mu;
    const float rs = rsqrtf(var + 1e-5f);
    const int idx = lane * 4;
    const float4 gg = *(const float4*)(g + idx);
    const float4 bb = *(const float4*)(bt + idx);
    ushort_t o0 = f2bf((v.x - mu) * rs * gg.x + bb.x);
    ushort_t o1 = f2bf((v.y - mu) * rs * gg.y + bb.y);
    ushort_t o2 = f2bf((v.z - mu) * rs * gg.z + bb.z);
    ushort_t o3 = f2bf((v.w - mu) * rs * gg.w + bb.w);
    uint2 pk;
    pk.x = (uint32_t)o0 | ((uint32_t)o1 << 16);
    pk.y = (uint32_t)o2 | ((uint32_t)o3 << 16);
    *(uint2*)(h + (size_t)token * H_SZ + idx) = pk;
}

// ---------------------------------------------------------------------------
// gram8_k: per (pair, 8-token block) precompute solve data. Record (48 f32):
//   [0..27]  W[i][j] (i>j, idx=i(i-1)/2+j): strictly-lower part of
//            (I+L)^{-1}, where L[i][j] = alpha_j * (k_i . k_j).
//   [28..35] alpha_i = beta_i / (|k_i|^2 + 1e-6)
//   [36..43] beta_i  (0 for token L-1; 1 for s-half; (t+1)/L for e-half)
// Token i=0 in a block is the HIGHEST token (t = 8*bi+7). 32768 waves.
// ---------------------------------------------------------------------------
__global__ __launch_bounds__(256) void gram8_k(
    const float* __restrict__ proj, float* __restrict__ g8)
{
    const int pair = blockIdx.y;               // 0..127
    const int b = pair >> 1;
    const int half = pair & 1;
    const int bi = blockIdx.x * 4 + (threadIdx.x >> 6);   // 0..255
    const int l = threadIdx.x & 63;

    const float* kbase = proj + (size_t)b * L_SZ * H_SZ + half * HALF_SZ;

    float kx[8], ky[8];
#pragma unroll
    for (int i = 0; i < 8; ++i) {
        const int tok = bi * 8 + 7 - i;
        const float2 t = *(const float2*)(kbase + (size_t)tok * H_SZ + 2 * l);
        kx[i] = t.x; ky[i] = t.y;
    }

    float r[36];
#pragma unroll
    for (int i = 0; i < 8; ++i)
        r[i] = kx[i] * kx[i] + ky[i] * ky[i];
#pragma unroll
    for (int i = 1; i < 8; ++i)
#pragma unroll
        for (int j = 0; j < i; ++j)
            r[8 + i * (i - 1) / 2 + j] = kx[i] * kx[j] + ky[i] * ky[j];

#pragma unroll
    for (int m = 1; m < 64; m <<= 1)
#pragma unroll
        for (int t = 0; t < 36; ++t)
            r[t] += __shfl_xor(r[t], m);

    const float invL = 1.0f / (float)L_SZ;
    float al[8], be[8];
#pragma unroll
    for (int i = 0; i < 8; ++i) {
        const int tok = bi * 8 + 7 - i;
        const float bet = (tok == L_SZ - 1)
            ? 0.f : (half ? (float)(tok + 1) * invL : 1.0f);
        be[i] = bet;
        al[i] = bet / (r[i] + 1e-6f);
    }

    // L (strictly lower), then W = (I+L)^{-1} - I by column-wise forward subst.
    float Lw[28];
#pragma unroll
    for (int i = 1; i < 8; ++i)
#pragma unroll
        for (int j = 0; j < i; ++j)
            Lw[i * (i - 1) / 2 + j] = al[j] * r[8 + i * (i - 1) / 2 + j];
    float Wv[28];
#pragma unroll
    for (int j = 0; j < 7; ++j)
#pragma unroll
        for (int i = j + 1; i < 8; ++i) {
            float s = Lw[i * (i - 1) / 2 + j];
#pragma unroll
            for (int m = j + 1; m < i; ++m)
                s += Lw[i * (i - 1) / 2 + m] * Wv[m * (m - 1) / 2 + j];
            Wv[i * (i - 1) / 2 + j] = -s;
        }

    if (l == 0) {
        float* out = g8 + ((size_t)pair * 256 + bi) * 48;
#pragma unroll
        for (int t = 0; t < 28; ++t) out[t] = Wv[t];
#pragma unroll
        for (int i = 0; i < 8; ++i) {
            out[28 + i] = al[i];
            out[36 + i] = be[i];
        }
    }
}

// ---------------------------------------------------------------------------
// scan_bw8_k: backward vector scan, W=8 windows, precomputed inverted Grams.
// EXACT REVERT to round-12 (measured best: 276 us, VGPR 128): immediate KEEP
// of the just-issued prefetch buffers at iteration end; no memory clobber.
// ---------------------------------------------------------------------------
__global__ __launch_bounds__(64, 1) void scan_bw8_k(
    const float* __restrict__ proj, const float* __restrict__ g8,
    float* __restrict__ cbuf)
{
    const int pair = blockIdx.x;        // 0..127
    const int b = pair >> 1;
    const int half = pair & 1;
    const int l = threadIdx.x;          // 0..63, owns elems 2l, 2l+1

    const float* kbase = proj + (size_t)b * L_SZ * H_SZ + half * HALF_SZ;
    const float* gbase = g8 + (size_t)pair * 256 * 48;

    float vx, vy, cx = 0.f, cy = 0.f;
    {
        const float2 q = *(const float2*)(kbase + (size_t)(L_SZ - 1) * H_SZ + 2 * l);
        vx = q.x; vy = q.y;
    }

    float kAx[8], kAy[8], kBx[8], kBy[8], kCx[8], kCy[8];
    float gA[48], gB[48], gC[48];

#define LOADK(KX, KY, blk) {                                                  \
    const int bb_ = (blk) < 0 ? 0 : (blk);                                    \
    const float* kb_ = kbase + (size_t)bb_ * 8 * H_SZ + 2 * l;                \
    _Pragma("unroll")                                                         \
    for (int i_ = 0; i_ < 8; ++i_) {                                          \
        const float2 t_ = *(const float2*)(kb_ + (size_t)(7 - i_) * H_SZ);    \
        KX[i_] = t_.x; KY[i_] = t_.y;                                         \
    } }

#define LOADG(GG, blk) {                                                      \
    const int bb_ = (blk) < 0 ? 0 : (blk);                                    \
    const float* gs_ = gbase + (size_t)bb_ * 48;                              \
    _Pragma("unroll")                                                         \
    for (int i_ = 0; i_ < 12; ++i_) {                                         \
        const float4 t_ = *(const float4*)(gs_ + 4 * i_);                     \
        GG[4*i_+0] = t_.x; GG[4*i_+1] = t_.y;                                 \
        GG[4*i_+2] = t_.z; GG[4*i_+3] = t_.w;                                 \
    } }

#define KEEP8(A0,A1,A2,A3,A4,A5,A6,A7)                                        \
    asm volatile("" :: "v"(A0), "v"(A1), "v"(A2), "v"(A3),                    \
                       "v"(A4), "v"(A5), "v"(A6), "v"(A7));

#define KEEPK(KX, KY)                                                         \
    KEEP8(KX[0],KX[1],KX[2],KX[3],KX[4],KX[5],KX[6],KX[7])                    \
    KEEP8(KY[0],KY[1],KY[2],KY[3],KY[4],KY[5],KY[6],KY[7])

#define KEEPG(GG)                                                             \
    KEEP8(GG[0],GG[1],GG[2],GG[3],GG[4],GG[5],GG[6],GG[7])                    \
    KEEP8(GG[8],GG[9],GG[10],GG[11],GG[12],GG[13],GG[14],GG[15])              \
    KEEP8(GG[16],GG[17],GG[18],GG[19],GG[20],GG[21],GG[22],GG[23])            \
    KEEP8(GG[24],GG[25],GG[26],GG[27],GG[28],GG[29],GG[30],GG[31])            \
    KEEP8(GG[32],GG[33],GG[34],GG[35],GG[36],GG[37],GG[38],GG[39])            \
    KEEP8(GG[40],GG[41],GG[42],GG[43],GG[44],GG[45],GG[46],GG[47])

// One 8-step window: use (KCX,KCY,GC); prefetch block (bi_-2) into (KFX,..,GF).
#define ITER(bi_, KCX, KCY, GC, KFX, KFY, GF, DOPF) {                         \
    if (DOPF) { LOADK(KFX, KFY, (bi_) - 2) LOADG(GF, (bi_) - 2) }             \
    float a_[8];                                                              \
    _Pragma("unroll")                                                         \
    for (int i_ = 0; i_ < 8; ++i_)                                            \
        a_[i_] = KCX[i_] * vx + KCY[i_] * vy;                                 \
    _Pragma("unroll")                                                         \
    for (int m_ = 1; m_ < 64; m_ <<= 1)                                       \
        _Pragma("unroll")                                                     \
        for (int i_ = 0; i_ < 8; ++i_)                                        \
            a_[i_] += __shfl_xor(a_[i_], m_);                                 \
    /* d = a + W a : independent terms, shallow trees */                      \
    float d_[8];                                                              \
    d_[0] = a_[0];                                                            \
    d_[1] = fmaf(GC[0], a_[0], a_[1]);                                        \
    d_[2] = fmaf(GC[1], a_[0], a_[2]) + GC[2] * a_[1];                        \
    d_[3] = (fmaf(GC[3], a_[0], a_[3]) + GC[4] * a_[1]) + GC[5] * a_[2];      \
    d_[4] = (fmaf(GC[6], a_[0], a_[4]) + GC[7] * a_[1])                       \
          + (GC[8] * a_[2] + GC[9] * a_[3]);                                  \
    d_[5] = ((fmaf(GC[10], a_[0], a_[5]) + GC[11] * a_[1])                    \
          + (GC[12] * a_[2] + GC[13] * a_[3])) + GC[14] * a_[4];              \
    d_[6] = ((fmaf(GC[15], a_[0], a_[6]) + GC[16] * a_[1])                    \
          + (GC[17] * a_[2] + GC[18] * a_[3]))                                \
          + (GC[19] * a_[4] + GC[20] * a_[5]);                                \
    d_[7] = ((fmaf(GC[21], a_[0], a_[7]) + GC[22] * a_[1])                    \
          + (GC[23] * a_[2] + GC[24] * a_[3]))                                \
          + ((GC[25] * a_[4] + GC[26] * a_[5]) + GC[27] * a_[6]);             \
    float ad_[8], bd_[8];                                                     \
    _Pragma("unroll")                                                         \
    for (int i_ = 0; i_ < 8; ++i_) {                                          \
        ad_[i_] = GC[28 + i_] * d_[i_];                                       \
        bd_[i_] = GC[36 + i_] * d_[i_];                                       \
    }                                                                         \
    const float sx_ = (fmaf(ad_[0], KCX[0], ad_[1] * KCX[1])                  \
                     + fmaf(ad_[2], KCX[2], ad_[3] * KCX[3]))                 \
                    + (fmaf(ad_[4], KCX[4], ad_[5] * KCX[5])                  \
                     + fmaf(ad_[6], KCX[6], ad_[7] * KCX[7]));                \
    const float sy_ = (fmaf(ad_[0], KCY[0], ad_[1] * KCY[1])                  \
                     + fmaf(ad_[2], KCY[2], ad_[3] * KCY[3]))                 \
                    + (fmaf(ad_[4], KCY[4], ad_[5] * KCY[5])                  \
                     + fmaf(ad_[6], KCY[6], ad_[7] * KCY[7]));                \
    const float tx_ = (fmaf(bd_[0], KCX[0], bd_[1] * KCX[1])                  \
                     + fmaf(bd_[2], KCX[2], bd_[3] * KCX[3]))                 \
                    + (fmaf(bd_[4], KCX[4], bd_[5] * KCX[5])                  \
                     + fmaf(bd_[6], KCX[6], bd_[7] * KCX[7]));                \
    const float ty_ = (fmaf(bd_[0], KCY[0], bd_[1] * KCY[1])                  \
                     + fmaf(bd_[2], KCY[2], bd_[3] * KCY[3]))                 \
                    + (fmaf(bd_[4], KCY[4], bd_[5] * KCY[5])                  \
                     + fmaf(bd_[6], KCY[6], bd_[7] * KCY[7]));                \
    vx -= sx_; vy -= sy_; cx += tx_; cy += ty_;                               \
    if (DOPF) { KEEPK(KFX, KFY) KEEPG(GF) }                                   \
    }

    // init: block 255 -> A, block 254 -> B
    LOADK(kAx, kAy, 255) LOADG(gA, 255)
    LOADK(kBx, kBy, 254) LOADG(gB, 254)

    int bi = 255;
#pragma unroll 1
    for (int t3 = 0; t3 < 85; ++t3) {
        ITER(bi,     kAx, kAy, gA, kCx, kCy, gC, 1)   // pf bi-2 -> C
        ITER(bi - 1, kBx, kBy, gB, kAx, kAy, gA, 1)   // pf bi-3 -> A
        ITER(bi - 2, kCx, kCy, gC, kBx, kBy, gB, 1)   // pf bi-4 -> B
        bi -= 3;
    }
    // after loop: bi == 0, block 0 resides in A (loaded when bi was 2)
    ITER(0, kAx, kAy, gA, kBx, kBy, gB, 0)

#undef ITER
#undef KEEPG
#undef KEEPK
#undef KEEP8
#undef LOADG
#undef LOADK

    cbuf[b * H_SZ + half * HALF_SZ + 2 * l] = cx;
    cbuf[b * H_SZ + half * HALF_SZ + 2 * l + 1] = cy;
}

// ---------------------------------------------------------------------------
// out[b, v] = sum_h c[b,h] * out_w[h,v] + out_b[v]   (f32 store)
// ---------------------------------------------------------------------------
__global__ __launch_bounds__(256) void out_k(
    const float* __restrict__ c, const float* __restrict__ w,
    const float* __restrict__ ob, float* __restrict__ out)
{
    const int b = blockIdx.x >> 2;
    const int v = ((blockIdx.x & 3) << 8) + threadIdx.x;
    const float* cb = c + b * H_SZ;
    float acc = ob[v];
#pragma unroll 4
    for (int hh = 0; hh < H_SZ; ++hh)
        acc = fmaf(cb[hh], w[(size_t)hh * V_SZ + v], acc);
    out[(size_t)b * V_SZ + v] = acc;
}

// ---------------------------------------------------------------------------
extern "C" void kernel_launch(void* const* d_in, const int* in_sizes, int n_in,
                              void* d_out, int out_size, void* d_ws, size_t ws_size,
                              hipStream_t stream)
{
    const int*   seq   = (const int*)d_in[0];
    const float* embed = (const float*)d_in[1];
    const float* w1    = (const float*)d_in[2];
    const float* b1    = (const float*)d_in[3];
    const float* w2    = (const float*)d_in[4];
    const float* b2    = (const float*)d_in[5];
    const float* ln_g  = (const float*)d_in[6];
    const float* ln_b  = (const float*)d_in[7];
    const float* kp_w  = (const float*)d_in[8];
    const float* kp_b  = (const float*)d_in[9];
    const float* out_w = (const float*)d_in[10];
    const float* out_b = (const float*)d_in[11];

    char* ws = (char*)d_ws;
    size_t off = 0;
    auto alloc = [&](size_t bytes) -> void* {
        void* p = ws + off;
        off += (bytes + 255) & ~(size_t)255;
        return p;
    };

    float*    proj = (float*)alloc((size_t)NTOK * H_SZ * sizeof(float));     // 128 MB
    ushort_t* t1_c = (ushort_t*)alloc((size_t)CH * 512 * sizeof(ushort_t));  // 16 MB
    float*    x_c  = (float*)alloc((size_t)CH * H_SZ * sizeof(float));       // 16 MB
    ushort_t* h_c  = (ushort_t*)alloc((size_t)CH * H_SZ * sizeof(ushort_t)); // 8 MB
    float*    g8   = (float*)alloc((size_t)128 * 256 * 48 * sizeof(float) + 256); // 6.3 MB
    float*    cbuf = (float*)alloc((size_t)B_SZ * H_SZ * sizeof(float));
    // bf16 weight copies
    ushort_t* embed_bf = (ushort_t*)alloc((size_t)V_SZ * H_SZ * 2);          // 512 KB
    ushort_t* w1T = (ushort_t*)alloc((size_t)512 * 256 * 2);                 // 256 KB
    ushort_t* w2T = (ushort_t*)alloc((size_t)256 * 512 * 2);                 // 256 KB
    ushort_t* kpT = (ushort_t*)alloc((size_t)256 * 256 * 2);                 // 128 KB
    float*    outp = (float*)d_out;

    const dim3 blk(256);

    // weight preconversion (bf16 / transposed-bf16)
    cvt_bf16_k<<<dim3((V_SZ * H_SZ) / 1024), blk, 0, stream>>>(
        embed, embed_bf, V_SZ * H_SZ);
    transpose_cvt_k<<<dim3((256 * 512) / 256), blk, 0, stream>>>(w1, w1T, 256, 512);
    transpose_cvt_k<<<dim3((512 * 256) / 256), blk, 0, stream>>>(w2, w2T, 512, 256);
    transpose_cvt_k<<<dim3((256 * 256) / 256), blk, 0, stream>>>(kp_w, kpT, 256, 256);

    for (int c = 0; c < NTOK / CH; ++c) {
        const int base = c * CH;
        const int* seq_c = seq + base;
        // GEMM1: t1 = relu(embed[seq] @ w1 + b1)     M=CH K=256 N=512
        gemm_mfma<1, 256, 512><<<dim3(CH / 128, 4), blk, 0, stream>>>(
            embed_bf, w1T, b1, t1_c, seq_c, nullptr);
        // GEMM2: x = t1 @ w2 + b2 + embed[seq]       M=CH K=512 N=256
        gemm_mfma<2, 512, 256><<<dim3(CH / 128, 2), blk, 0, stream>>>(
            t1_c, w2T, b2, x_c, seq_c, embed);
        // LN: h = LN(x) * g + b  (bf16)
        ln_k<<<dim3(CH / 4), blk, 0, stream>>>(x_c, ln_g, ln_b, h_c);
        // GEMM3: proj = h @ kp_w + kp_b              M=CH K=256 N=256
        gemm_mfma<3, 256, 256><<<dim3(CH / 128, 2), blk, 0, stream>>>(
            h_c, kpT, kp_b, proj + (size_t)base * H_SZ, seq_c, nullptr);
    }

    // parallel precompute of inverted 8x8 block Grams + coefficients
    gram8_k<<<dim3(64, 128), blk, 0, stream>>>(proj, g8);
    // serial backward vector scan with precomputed inverted Grams
    scan_bw8_k<<<dim3(128), dim3(64), 0, stream>>>(proj, g8, cbuf);
    out_k<<<dim3(B_SZ * 4), blk, 0, stream>>>(cbuf, out_w, out_b, outp);
}